// Round 1
// baseline (111.802 us; speedup 1.0000x reference)
//
#include <hip/hip_runtime.h>

// Problem constants (from reference)
#define B_SZ   256
#define L_SZ   200
#define EMBED  128
#define MAX_G  8
#define NTOK   (B_SZ * L_SZ)        // 51200 tokens
#define F4_PER_ROW (EMBED / 4)      // 32 float4 per embedding row
#define TOK_PER_BLK 8               // 8 tokens per 256-thread block

typedef float nativef4 __attribute__((ext_vector_type(4)));  // for nontemporal store

// 32 lanes per token, each lane owns one float4 of the 128-float row.
// Grid = (25, 256): blockIdx.x covers L in chunks of 8 (no % needed),
// blockIdx.y = batch index. 25*8 = 200 = L exactly, so no tail check.
//
// __launch_bounds__(256, 8): 8 waves/SIMD (32 waves/CU) -> caps VGPRs at 64.
// The genre accumulation is split into two batches of 4 rows so only 16
// VGPRs of genre data are live at once (vs 32 before), keeping us under the
// 64-VGPR occupancy cliff. The extra L1-hit latency of the second batch is
// hidden under the token-row L3/HBM gather (~600-900 cy), which dominates
// the per-token critical path.
__global__ __launch_bounds__(256, 8) void bert_embed_kernel(
    const int*    __restrict__ seq,       // [B,L]
    const float4* __restrict__ tok_tab,   // [VOCAB, 32] (float4 view)
    const float4* __restrict__ gen_tab,   // [21, 32]
    const float4* __restrict__ pos_tab,   // [200, 32]
    const int*    __restrict__ tgid,      // [VOCAB, 8]
    const int*    __restrict__ gcnt,      // [VOCAB]
    float4*       __restrict__ out)       // [B,L,32]
{
    const int tid   = threadIdx.x;
    const int group = tid >> 5;          // token slot within block (0..7)
    const int lane  = tid & 31;          // float4 index within row (0..31)

    const int l = blockIdx.x * TOK_PER_BLK + group;  // 0..199
    const int b = blockIdx.y;                        // 0..255
    const int token_idx = b * L_SZ + l;

    const int t = seq[token_idx];

    // Issue all t-dependent control loads + the two big row loads up front.
    const float4 tokv = tok_tab[(long)t * F4_PER_ROW + lane];
    const float4 p    = pos_tab[l * F4_PER_ROW + lane];
    const int    cnt  = gcnt[t];                     // in [1, 8]

    // 8 genre ids = 32B contiguous, always-valid memory (table is [VOCAB][8]).
    const int4* g4 = (const int4*)(tgid + (long)t * MAX_G);
    const int4  ga = g4[0];
    const int4  gb = g4[1];

    const float inv = 1.0f / (float)cnt;

    // ---- Batch 1: genre rows 0..3 (10.75 KB table, L1-hot) ----
    float4 r0 = gen_tab[ga.x * F4_PER_ROW + lane];
    float4 r1 = gen_tab[ga.y * F4_PER_ROW + lane];
    float4 r2 = gen_tab[ga.z * F4_PER_ROW + lane];
    float4 r3 = gen_tab[ga.w * F4_PER_ROW + lane];

    nativef4 acc;
    acc.x = tokv.x + p.x;
    acc.y = tokv.y + p.y;
    acc.z = tokv.z + p.z;
    acc.w = tokv.w + p.w;

    {
        const float w0 = inv;                         // cnt >= 1 always
        const float w1 = (1 < cnt) ? inv : 0.0f;
        const float w2 = (2 < cnt) ? inv : 0.0f;
        const float w3 = (3 < cnt) ? inv : 0.0f;
        acc.x = fmaf(w0, r0.x, acc.x); acc.y = fmaf(w0, r0.y, acc.y);
        acc.z = fmaf(w0, r0.z, acc.z); acc.w = fmaf(w0, r0.w, acc.w);
        acc.x = fmaf(w1, r1.x, acc.x); acc.y = fmaf(w1, r1.y, acc.y);
        acc.z = fmaf(w1, r1.z, acc.z); acc.w = fmaf(w1, r1.w, acc.w);
        acc.x = fmaf(w2, r2.x, acc.x); acc.y = fmaf(w2, r2.y, acc.y);
        acc.z = fmaf(w2, r2.z, acc.z); acc.w = fmaf(w2, r2.w, acc.w);
        acc.x = fmaf(w3, r3.x, acc.x); acc.y = fmaf(w3, r3.y, acc.y);
        acc.z = fmaf(w3, r3.z, acc.z); acc.w = fmaf(w3, r3.w, acc.w);
    }

    // ---- Batch 2: genre rows 4..7 (reuses r0..r3 registers) ----
    r0 = gen_tab[gb.x * F4_PER_ROW + lane];
    r1 = gen_tab[gb.y * F4_PER_ROW + lane];
    r2 = gen_tab[gb.z * F4_PER_ROW + lane];
    r3 = gen_tab[gb.w * F4_PER_ROW + lane];

    {
        const float w4 = (4 < cnt) ? inv : 0.0f;
        const float w5 = (5 < cnt) ? inv : 0.0f;
        const float w6 = (6 < cnt) ? inv : 0.0f;
        const float w7 = (7 < cnt) ? inv : 0.0f;
        acc.x = fmaf(w4, r0.x, acc.x); acc.y = fmaf(w4, r0.y, acc.y);
        acc.z = fmaf(w4, r0.z, acc.z); acc.w = fmaf(w4, r0.w, acc.w);
        acc.x = fmaf(w5, r1.x, acc.x); acc.y = fmaf(w5, r1.y, acc.y);
        acc.z = fmaf(w5, r1.z, acc.z); acc.w = fmaf(w5, r1.w, acc.w);
        acc.x = fmaf(w6, r2.x, acc.x); acc.y = fmaf(w6, r2.y, acc.y);
        acc.z = fmaf(w6, r2.z, acc.z); acc.w = fmaf(w6, r2.w, acc.w);
        acc.x = fmaf(w7, r3.x, acc.x); acc.y = fmaf(w7, r3.y, acc.y);
        acc.z = fmaf(w7, r3.z, acc.z); acc.w = fmaf(w7, r3.w, acc.w);
    }

    // Nontemporal store: output has zero reuse; keep L2/L3 for the gathers.
    nativef4* dst = (nativef4*)&out[(long)token_idx * F4_PER_ROW + lane];
    __builtin_nontemporal_store(acc, dst);
}

extern "C" void kernel_launch(void* const* d_in, const int* in_sizes, int n_in,
                              void* d_out, int out_size, void* d_ws, size_t ws_size,
                              hipStream_t stream) {
    const int*    seq     = (const int*)   d_in[0];  // sequence (256,200) int32
    const float4* tok_tab = (const float4*)d_in[1];  // token_table (100000,128) f32
    const float4* gen_tab = (const float4*)d_in[2];  // genre_table (21,128) f32
    const float4* pos_tab = (const float4*)d_in[3];  // pos_table (200,128) f32
    const int*    tgid    = (const int*)   d_in[4];  // token_genre_ids (100000,8)
    const int*    gcnt    = (const int*)   d_in[5];  // genre_counts (100000,)
    float4*       out     = (float4*)      d_out;    // (256,200,128) f32

    dim3 grid(L_SZ / TOK_PER_BLK, B_SZ);  // (25, 256) = 6400 blocks, no tail
    bert_embed_kernel<<<grid, 256, 0, stream>>>(seq, tok_tab, gen_tab,
                                                pos_tab, tgid, gcnt, out);
}